// Round 13
// baseline (210.997 us; speedup 1.0000x reference)
//
#include <hip/hip_runtime.h>
#include <hip/hip_bf16.h>

typedef __attribute__((ext_vector_type(8))) short short8;
typedef __attribute__((ext_vector_type(4))) float f32x4;
typedef __attribute__((ext_vector_type(16))) float f32x16;
typedef float f32x4u __attribute__((ext_vector_type(4), aligned(4)));
typedef __attribute__((ext_vector_type(4))) unsigned short u16x4;
typedef __attribute__((ext_vector_type(2))) unsigned int u32x2;
typedef __attribute__((ext_vector_type(4))) unsigned int u32x4;
typedef __hip_bfloat16 bf16;

#define SCALE_Q 0.18033688f  // d^-0.5 * log2(e)

#define GLD_LDS16(g, l) __builtin_amdgcn_global_load_lds(                      \
    (const __attribute__((address_space(1))) void*)(g),                        \
    (__attribute__((address_space(3))) void*)(l), 16, 0, 0)

static __device__ __forceinline__ f32x4 mfma16(short8 a, short8 b, f32x4 c) {
  return __builtin_amdgcn_mfma_f32_16x16x32_bf16(a, b, c, 0, 0, 0);
}
static __device__ __forceinline__ f32x16 mfma32(short8 a, short8 b, f32x16 c) {
  return __builtin_amdgcn_mfma_f32_32x32x16_bf16(a, b, c, 0, 0, 0);
}

// packed f32x2 -> bf16x2 convert (single HW instr; no builtin on gfx950)
static __device__ __forceinline__ unsigned cvtpk(float lo, float hi) {
  unsigned r;
  asm("v_cvt_pk_bf16_f32 %0, %1, %2" : "=v"(r) : "v"(lo), "v"(hi));
  return r;
}

// raw v_exp_f32 (D = 2^S0): avoids libm's denormal-fixup sequence
static __device__ __forceinline__ float fexp2(float x) {
  float r;
  asm("v_exp_f32 %0, %1" : "=v"(r) : "v"(x));
  return r;
}

// vdst upper 32 lanes <-> vsrc lower 32 lanes. ONLY use with operands that
// hold DISTINCT values (identical-copy operands can be register-coalesced by
// the allocator -> self-swap bug; scalar reductions use __shfl_xor instead).
#define PLSWAP(a, b) asm("v_permlane32_swap_b32 %0, %1" : "+v"(a), "+v"(b))

// ---------------- fused preprocessing: 3x fp32->bf16 cvt + bias table -------
// blocks [0,4096): x->xb; [4096,7168): Wqkv->wqb; [7168,8192): Wout->wob;
// [8192,8256): relpf[h][i] = rel[clamp(i-2047,±1024)+1024][h]*log2(e) - 16
// (fixed softmax max baked in; scores bounded, bf16 keeps relative precision)
__global__ __launch_bounds__(256) void k_pre(
    const float* __restrict__ x, const float* __restrict__ Wqkv,
    const float* __restrict__ Wout, const float* __restrict__ rel,
    bf16* __restrict__ xb, bf16* __restrict__ wqb, bf16* __restrict__ wob,
    float* __restrict__ relpf) {
  int bid = blockIdx.x;
  if (bid < 8192) {
    const float* in;
    bf16* out;
    long i;
    if (bid < 4096) {
      in = x; out = xb; i = (long)bid * 256 + threadIdx.x;
    } else if (bid < 7168) {
      in = Wqkv; out = wqb; i = (long)(bid - 4096) * 256 + threadIdx.x;
    } else {
      in = Wout; out = wob; i = (long)(bid - 7168) * 256 + threadIdx.x;
    }
    f32x4 v = *(const f32x4*)(in + i * 4);
    u16x4 o;
#pragma unroll
    for (int j = 0; j < 4; ++j)
      o[j] = __builtin_bit_cast(unsigned short, __float2bfloat16(v[j]));
    *(u16x4*)((unsigned short*)out + i * 4) = o;
  } else {
    int base = (bid - 8192) * 1024 + threadIdx.x;
#pragma unroll
    for (int k = 0; k < 4; ++k) {
      int i = base + k * 256;  // 0..65535
      int h = i >> 12, ii = i & 4095;
      int dd = ii - 2047;
      dd = dd < -1024 ? -1024 : (dd > 1024 ? 1024 : dd);
      relpf[i] = rel[(size_t)(dd + 1024) * 16 + h] * 1.44269504f - 16.0f;
    }
  }
}

// ---------------- 128x128 bf16 GEMM, 3-buf counted-vmcnt pipeline -----------
// B stored [N][K]. mfma operands SWAPPED (bfv, af) -> lane holds 4 consecutive
// N-columns. Single raw barrier per K-step + s_waitcnt vmcnt(4).
// epi==0: scatter Q/K [bh][2048][64] (Q pre-scaled), V DIRECTLY TRANSPOSED
//         into Vt [bh][64][2048].
// epi==1: fp32 out[t*N+e] = acc + bias[e], 16B stores.
__global__ __launch_bounds__(256, 3) void k_gemm(
    const bf16* __restrict__ A, const bf16* __restrict__ B,
    int M, int N, int K, int epi,
    bf16* __restrict__ Qb, bf16* __restrict__ Kb, bf16* __restrict__ Vt,
    float* __restrict__ Out, const float* __restrict__ bias) {
  __shared__ bf16 lA[3][4096];  // 3 x (128 x 32)
  __shared__ bf16 lB[3][4096];
  const int tid = threadIdx.x, w = tid >> 6, l = tid & 63;
  const int m0 = blockIdx.x * 128, n0 = blockIdx.y * 128;
  const int wrow = (w >> 1) * 64, wcol = (w & 1) * 64;
  const int fr = l & 15, fq = l >> 4;
  f32x4 acc[4][4] = {};
  const int c0 = w * 64 + l, c1 = c0 + 256;  // 16B chunk ids
  const bf16* Ag0 = A + (size_t)(m0 + (c0 >> 2)) * K + (c0 & 3) * 8;
  const bf16* Ag1 = A + (size_t)(m0 + (c1 >> 2)) * K + (c1 & 3) * 8;
  const bf16* Bg0 = B + (size_t)(n0 + (c0 >> 2)) * K + (c0 & 3) * 8;
  const bf16* Bg1 = B + (size_t)(n0 + (c1 >> 2)) * K + (c1 & 3) * 8;
  bf16* lA0 = &lA[0][w * 512];
  bf16* lA1 = &lA[0][2048 + w * 512];
  bf16* lB0 = &lB[0][w * 512];
  bf16* lB1 = &lB[0][2048 + w * 512];

#define GSTAGE(T, BI)                                                          \
  do {                                                                         \
    const int ko_ = (T) * 32;                                                  \
    GLD_LDS16(Ag0 + ko_, lA0 + (BI) * 4096);                                   \
    GLD_LDS16(Ag1 + ko_, lA1 + (BI) * 4096);                                   \
    GLD_LDS16(Bg0 + ko_, lB0 + (BI) * 4096);                                   \
    GLD_LDS16(Bg1 + ko_, lB1 + (BI) * 4096);                                   \
  } while (0)

  const int nk = K >> 5;
  GSTAGE(0, 0);
  __builtin_amdgcn_sched_barrier(0);
  GSTAGE(1, 1);
  __builtin_amdgcn_sched_barrier(0);

  int bc_ = 0, bs_ = 2;
  for (int t = 0; t < nk; ++t) {
    asm volatile("s_waitcnt vmcnt(4)" ::: "memory");  // stage(t) done
    __builtin_amdgcn_s_barrier();                     // all waves' stage(t)
    __builtin_amdgcn_sched_barrier(0);
    int tt = (t + 2 < nk) ? t + 2 : nk - 1;  // clamp keeps count invariant
    GSTAGE(tt, bs_);
    __builtin_amdgcn_sched_barrier(0);
    const bf16* pA = &lA[bc_][0];
    const bf16* pB = &lB[bc_][0];
    short8 af[4], bfv[4];
#pragma unroll
    for (int mi = 0; mi < 4; ++mi)
      af[mi] = *(const short8*)&pA[(wrow + mi * 16 + fr) * 32 + fq * 8];
#pragma unroll
    for (int ni = 0; ni < 4; ++ni)
      bfv[ni] = *(const short8*)&pB[(wcol + ni * 16 + fr) * 32 + fq * 8];
    __builtin_amdgcn_s_setprio(1);
#pragma unroll
    for (int mi = 0; mi < 4; ++mi)
#pragma unroll
      for (int ni = 0; ni < 4; ++ni)
        acc[mi][ni] = mfma16(bfv[ni], af[mi], acc[mi][ni]);  // transposed
    __builtin_amdgcn_s_setprio(0);
    bc_ = (bc_ == 2) ? 0 : bc_ + 1;
    bs_ = (bs_ == 2) ? 0 : bs_ + 1;
  }
#undef GSTAGE

  if (epi == 0) {
#pragma unroll
    for (int mi = 0; mi < 4; ++mi)
#pragma unroll
      for (int ni = 0; ni < 4; ++ni) {
        int t = m0 + wrow + mi * 16 + fr;          // lane-fixed token
        int e4 = n0 + wcol + ni * 16 + fq * 4;     // 4 consecutive cols
        int sect = e4 >> 10, eh = (e4 >> 6) & 15, dh = e4 & 63;
        int b = t >> 11, tt = t & 2047;
        f32x4 a = acc[mi][ni];
        if (sect < 2) {
          size_t idx = (((size_t)b * 16 + eh) * 2048 + tt) * 64 + dh;
          float sc = (sect == 0) ? SCALE_Q : 1.f;  // pre-scale Q
          u32x2 ov;
          ov[0] = cvtpk(a[0] * sc, a[1] * sc);
          ov[1] = cvtpk(a[2] * sc, a[3] * sc);
          bf16* dst = (sect == 0) ? Qb : Kb;
          *(u32x2*)(dst + idx) = ov;
        } else {
          // V directly transposed: Vt[bh][d][t], 16-lane-contiguous 2B stores
          size_t vb = ((size_t)((b << 4) + eh) * 64 + dh) * 2048 + tt;
          unsigned p0 = cvtpk(a[0], a[1]);
          unsigned p1 = cvtpk(a[2], a[3]);
          unsigned short* vp = (unsigned short*)Vt;
          vp[vb] = (unsigned short)p0;
          vp[vb + 2048] = (unsigned short)(p0 >> 16);
          vp[vb + 4096] = (unsigned short)p1;
          vp[vb + 6144] = (unsigned short)(p1 >> 16);
        }
      }
  } else {
#pragma unroll
    for (int mi = 0; mi < 4; ++mi)
#pragma unroll
      for (int ni = 0; ni < 4; ++ni) {
        int t = m0 + wrow + mi * 16 + fr;
        int e4 = n0 + wcol + ni * 16 + fq * 4;
        f32x4 bv = *(const f32x4*)(bias + e4);
        f32x4 a = acc[mi][ni];
        f32x4 o = {a[0] + bv[0], a[1] + bv[1], a[2] + bv[2], a[3] + bv[3]};
        *(f32x4*)(Out + (size_t)t * N + e4) = o;
      }
  }
}

// ---------------- flash attention: L2-direct, NO LDS, NO barriers -----------
// K+V per head = 512 KB; XCD swizzle -> 4 heads (2 MB) resident per XCD L2.
// All K/V fragments read directly from global (L2-hot). No staging, no
// barriers, no vmcnt: the 4 waves/block run free and drift into phase
// offsets, so one wave's exp (VALU/trans) overlaps the other's MFMA on the
// same SIMD (guide m169 lesson: don't stage what L2 fits). Fixed softmax max
// (-16 baked into bias table). P built in-register (cvt_pk + permlane swap).
// Bias loads per-kb (16-reg liveness) to stay under the (256,2) VGPR cap.
__global__ __launch_bounds__(256, 2) void k_attn(
    const bf16* __restrict__ Qb, const bf16* __restrict__ Kb,
    const bf16* __restrict__ Vt, const float* __restrict__ relpf,
    bf16* __restrict__ AO) {
  const int id = blockIdx.x;            // 0..511
  const int xcd = id & 7, j = id >> 3;  // j: 0..63
  const int bh = xcd * 4 + (j >> 4), qt = j & 15;
  const int h = bh & 15, b = bh >> 4;
  const int tid = threadIdx.x, w = tid >> 6, l = tid & 63;
  const int r32 = l & 31, hl = l >> 5;
  const int q0w = qt * 128 + w * 32;

  // per-lane fragment bases (L2-hot)
  const bf16* Kf = Kb + (size_t)bh * 2048 * 64 + (size_t)r32 * 64 + hl * 8;
  const bf16* Vf = Vt + (size_t)bh * 64 * 2048 + (size_t)r32 * 2048 + hl * 8;

  // Q as B-operand: col q = r32, k(d) = ks*16 + hl*8 + j  (pre-scaled)
  const bf16* Qp = Qb + ((size_t)bh * 2048 + q0w + r32) * 64;
  short8 qf[4];
#pragma unroll
  for (int ks = 0; ks < 4; ++ks)
    qf[ks] = *(const short8*)(Qp + ks * 16 + hl * 8);

  // bias: idx = kv - q + 2047; kv = kt + kb*32 + (reg&3) + 8*(reg>>2) + 4*hl
  const float* bp = relpf + h * 4096 + (2047 + 4 * hl - q0w - r32);

  float llane = 0.f;
  f32x16 o0 = {}, o1 = {};

#pragma unroll 1
  for (int t = 0; t < 16; ++t) {
    const int kt = t * 128;
    // ---- S^T = K Q^T : K frags straight from L2
    f32x16 s[4] = {};
    __builtin_amdgcn_s_setprio(1);
#pragma unroll
    for (int kb = 0; kb < 4; ++kb)
#pragma unroll
      for (int ks = 0; ks < 4; ++ks) {
        short8 kf = *(const short8*)(Kf + (size_t)(kt + kb * 32) * 64 +
                                     ks * 16);
        s[kb] = mfma32(kf, qf[ks], s[kb]);
      }
    __builtin_amdgcn_s_setprio(0);
    // ---- fixed-max softmax: P = exp2(s + bias'), bias' has -16 baked in
    float ra[4] = {0.f, 0.f, 0.f, 0.f};
#pragma unroll
    for (int kb = 0; kb < 4; ++kb) {
      f32x4u bv[4];
#pragma unroll
      for (int g = 0; g < 4; ++g)
        bv[g] = *(const f32x4u*)(bp + kt + kb * 32 + 8 * g);
#pragma unroll
      for (int reg = 0; reg < 16; ++reg) {
        float e = fexp2(s[kb][reg] + bv[reg >> 2][reg & 3]);
        s[kb][reg] = e;
        ra[reg & 3] += e;
      }
    }
    llane += (ra[0] + ra[1]) + (ra[2] + ra[3]);
    // ---- P-frags in-register + PV: O^T[d][q] += V^T P, V frags from L2
#pragma unroll
    for (int kb = 0; kb < 4; ++kb) {
#pragma unroll
      for (int kh = 0; kh < 2; ++kh) {
        const int e = kh * 8;
        unsigned a0 = cvtpk(s[kb][e + 0], s[kb][e + 1]);
        unsigned a1 = cvtpk(s[kb][e + 2], s[kb][e + 3]);
        unsigned b0 = cvtpk(s[kb][e + 4], s[kb][e + 5]);
        unsigned b1 = cvtpk(s[kb][e + 6], s[kb][e + 7]);
        PLSWAP(a0, b0);  // distinct values: no coalescing hazard
        PLSWAP(a1, b1);
        u32x4 pw = {a0, a1, b0, b1};
        short8 pf = __builtin_bit_cast(short8, pw);
        const int ks = kb * 2 + kh;
        short8 v0 = *(const short8*)(Vf + kt + ks * 16);
        short8 v1 = *(const short8*)(Vf + 32 * 2048 + kt + ks * 16);
        __builtin_amdgcn_s_setprio(1);
        o0 = mfma32(v0, pf, o0);
        o1 = mfma32(v1, pf, o1);
        __builtin_amdgcn_s_setprio(0);
      }
    }
  }

  // lane: q = r32; o[db][reg] = O^T[d = db*32 + (reg&3)+8*(reg>>2)+4*hl][q]
  float lsum = llane + __shfl_xor(llane, 32);  // pair-combine once
  float rin = 1.f / lsum;
  bf16* aor = AO + ((size_t)(b * 2048 + q0w + r32)) * 1024 + h * 64 + hl * 4;
#pragma unroll
  for (int rg = 0; rg < 4; ++rg) {
    u32x2 ov0, ov1;
    ov0[0] = cvtpk(o0[4 * rg + 0] * rin, o0[4 * rg + 1] * rin);
    ov0[1] = cvtpk(o0[4 * rg + 2] * rin, o0[4 * rg + 3] * rin);
    *(u32x2*)(aor + rg * 8) = ov0;
    ov1[0] = cvtpk(o1[4 * rg + 0] * rin, o1[4 * rg + 1] * rin);
    ov1[1] = cvtpk(o1[4 * rg + 2] * rin, o1[4 * rg + 3] * rin);
    *(u32x2*)(aor + 32 + rg * 8) = ov1;
  }
}

// ---------------------------------------------------------------------------
extern "C" void kernel_launch(void* const* d_in, const int* in_sizes, int n_in,
                              void* d_out, int out_size, void* d_ws,
                              size_t ws_size, hipStream_t stream) {
  const float* x = (const float*)d_in[0];     // [2,2048,1024]
  const float* Wqkv = (const float*)d_in[1];  // [3072,1024]
  const float* Wout = (const float*)d_in[2];  // [1024,1024]
  const float* bout = (const float*)d_in[3];  // [1024]
  const float* rel = (const float*)d_in[4];   // [2049,16]
  float* out = (float*)d_out;

  char* p = (char*)d_ws;
  bf16* xb  = (bf16*)(p);                      // 8 MB  [4096][1024]
  bf16* wqb = (bf16*)(p + (8ull << 20));       // 6 MB  [3072][1024]
  bf16* wob = (bf16*)(p + (14ull << 20));      // 2 MB  [1024][1024]
  bf16* Qb  = (bf16*)(p + (16ull << 20));      // 8 MB  [32][2048][64]
  bf16* Kb  = (bf16*)(p + (24ull << 20));      // 8 MB
  bf16* Vtr = (bf16*)(p + (32ull << 20));      // 8 MB  [32][64][2048]
  bf16* aob = (bf16*)(p + (40ull << 20));      // 8 MB  [4096][1024]
  float* relpf = (float*)(p + (48ull << 20));  // 256 KB [16][4096] f32

  k_pre<<<8256, 256, 0, stream>>>(x, Wqkv, Wout, rel, xb, wqb, wob, relpf);
  k_gemm<<<dim3(32, 24), 256, 0, stream>>>(xb, wqb, 4096, 3072, 1024, 0,
                                           Qb, Kb, Vtr, nullptr, nullptr);
  k_attn<<<512, 256, 0, stream>>>(Qb, Kb, Vtr, relpf, aob);
  k_gemm<<<dim3(32, 8), 256, 0, stream>>>(aob, wob, 4096, 1024, 1024, 1,
                                          nullptr, nullptr, nullptr, out, bout);
}

// Round 14
// 122.049 us; speedup vs baseline: 1.7288x; 1.7288x over previous
//
#include <hip/hip_runtime.h>
#include <hip/hip_bf16.h>

typedef __attribute__((ext_vector_type(8))) short short8;
typedef __attribute__((ext_vector_type(4))) float f32x4;
typedef __attribute__((ext_vector_type(16))) float f32x16;
typedef float f32x4u __attribute__((ext_vector_type(4), aligned(4)));
typedef __attribute__((ext_vector_type(4))) unsigned short u16x4;
typedef __attribute__((ext_vector_type(2))) unsigned int u32x2;
typedef __attribute__((ext_vector_type(4))) unsigned int u32x4;
typedef __hip_bfloat16 bf16;

#define SCALE_Q 0.18033688f  // d^-0.5 * log2(e)

#define GLD_LDS16(g, l) __builtin_amdgcn_global_load_lds(                      \
    (const __attribute__((address_space(1))) void*)(g),                        \
    (__attribute__((address_space(3))) void*)(l), 16, 0, 0)

static __device__ __forceinline__ f32x4 mfma16(short8 a, short8 b, f32x4 c) {
  return __builtin_amdgcn_mfma_f32_16x16x32_bf16(a, b, c, 0, 0, 0);
}
static __device__ __forceinline__ f32x16 mfma32(short8 a, short8 b, f32x16 c) {
  return __builtin_amdgcn_mfma_f32_32x32x16_bf16(a, b, c, 0, 0, 0);
}

// packed f32x2 -> bf16x2 convert (single HW instr; no builtin on gfx950)
static __device__ __forceinline__ unsigned cvtpk(float lo, float hi) {
  unsigned r;
  asm("v_cvt_pk_bf16_f32 %0, %1, %2" : "=v"(r) : "v"(lo), "v"(hi));
  return r;
}

// raw v_exp_f32 (D = 2^S0): avoids libm's denormal-fixup sequence
static __device__ __forceinline__ float fexp2(float x) {
  float r;
  asm("v_exp_f32 %0, %1" : "=v"(r) : "v"(x));
  return r;
}

// vdst upper 32 lanes <-> vsrc lower 32 lanes. ONLY use with operands that
// hold DISTINCT values (identical-copy operands can be register-coalesced by
// the allocator -> self-swap bug; scalar reductions use __shfl_xor instead).
#define PLSWAP(a, b) asm("v_permlane32_swap_b32 %0, %1" : "+v"(a), "+v"(b))

// ---------------- fused preprocessing: 3x fp32->bf16 cvt + bias table -------
// blocks [0,4096): x->xb; [4096,7168): Wqkv->wqb; [7168,8192): Wout->wob;
// [8192,8256): relpf[h][i] = rel[clamp(i-2047,±1024)+1024][h]*log2(e) - 16
// (fixed softmax max baked in; scores bounded, bf16 keeps relative precision)
__global__ __launch_bounds__(256) void k_pre(
    const float* __restrict__ x, const float* __restrict__ Wqkv,
    const float* __restrict__ Wout, const float* __restrict__ rel,
    bf16* __restrict__ xb, bf16* __restrict__ wqb, bf16* __restrict__ wob,
    float* __restrict__ relpf) {
  int bid = blockIdx.x;
  if (bid < 8192) {
    const float* in;
    bf16* out;
    long i;
    if (bid < 4096) {
      in = x; out = xb; i = (long)bid * 256 + threadIdx.x;
    } else if (bid < 7168) {
      in = Wqkv; out = wqb; i = (long)(bid - 4096) * 256 + threadIdx.x;
    } else {
      in = Wout; out = wob; i = (long)(bid - 7168) * 256 + threadIdx.x;
    }
    f32x4 v = *(const f32x4*)(in + i * 4);
    u16x4 o;
#pragma unroll
    for (int j = 0; j < 4; ++j)
      o[j] = __builtin_bit_cast(unsigned short, __float2bfloat16(v[j]));
    *(u16x4*)((unsigned short*)out + i * 4) = o;
  } else {
    int base = (bid - 8192) * 1024 + threadIdx.x;
#pragma unroll
    for (int k = 0; k < 4; ++k) {
      int i = base + k * 256;  // 0..65535
      int h = i >> 12, ii = i & 4095;
      int dd = ii - 2047;
      dd = dd < -1024 ? -1024 : (dd > 1024 ? 1024 : dd);
      relpf[i] = rel[(size_t)(dd + 1024) * 16 + h] * 1.44269504f - 16.0f;
    }
  }
}

// ---------------- 128x128 bf16 GEMM, 3-buf counted-vmcnt pipeline -----------
// B stored [N][K]. mfma operands SWAPPED (bfv, af) -> lane holds 4 consecutive
// N-columns. Single raw barrier per K-step + s_waitcnt vmcnt(4).
// epi==0: scatter Q/K [bh][2048][64] (Q pre-scaled), V DIRECTLY TRANSPOSED
//         into Vt [bh][64][2048].
// epi==1: fp32 out[t*N+e] = acc + bias[e], 16B stores.
__global__ __launch_bounds__(256, 3) void k_gemm(
    const bf16* __restrict__ A, const bf16* __restrict__ B,
    int M, int N, int K, int epi,
    bf16* __restrict__ Qb, bf16* __restrict__ Kb, bf16* __restrict__ Vt,
    float* __restrict__ Out, const float* __restrict__ bias) {
  __shared__ bf16 lA[3][4096];  // 3 x (128 x 32)
  __shared__ bf16 lB[3][4096];
  const int tid = threadIdx.x, w = tid >> 6, l = tid & 63;
  const int m0 = blockIdx.x * 128, n0 = blockIdx.y * 128;
  const int wrow = (w >> 1) * 64, wcol = (w & 1) * 64;
  const int fr = l & 15, fq = l >> 4;
  f32x4 acc[4][4] = {};
  const int c0 = w * 64 + l, c1 = c0 + 256;  // 16B chunk ids
  const bf16* Ag0 = A + (size_t)(m0 + (c0 >> 2)) * K + (c0 & 3) * 8;
  const bf16* Ag1 = A + (size_t)(m0 + (c1 >> 2)) * K + (c1 & 3) * 8;
  const bf16* Bg0 = B + (size_t)(n0 + (c0 >> 2)) * K + (c0 & 3) * 8;
  const bf16* Bg1 = B + (size_t)(n0 + (c1 >> 2)) * K + (c1 & 3) * 8;
  bf16* lA0 = &lA[0][w * 512];
  bf16* lA1 = &lA[0][2048 + w * 512];
  bf16* lB0 = &lB[0][w * 512];
  bf16* lB1 = &lB[0][2048 + w * 512];

#define GSTAGE(T, BI)                                                          \
  do {                                                                         \
    const int ko_ = (T) * 32;                                                  \
    GLD_LDS16(Ag0 + ko_, lA0 + (BI) * 4096);                                   \
    GLD_LDS16(Ag1 + ko_, lA1 + (BI) * 4096);                                   \
    GLD_LDS16(Bg0 + ko_, lB0 + (BI) * 4096);                                   \
    GLD_LDS16(Bg1 + ko_, lB1 + (BI) * 4096);                                   \
  } while (0)

  const int nk = K >> 5;
  GSTAGE(0, 0);
  __builtin_amdgcn_sched_barrier(0);
  GSTAGE(1, 1);
  __builtin_amdgcn_sched_barrier(0);

  int bc_ = 0, bs_ = 2;
  for (int t = 0; t < nk; ++t) {
    asm volatile("s_waitcnt vmcnt(4)" ::: "memory");  // stage(t) done
    __builtin_amdgcn_s_barrier();                     // all waves' stage(t)
    __builtin_amdgcn_sched_barrier(0);
    int tt = (t + 2 < nk) ? t + 2 : nk - 1;  // clamp keeps count invariant
    GSTAGE(tt, bs_);
    __builtin_amdgcn_sched_barrier(0);
    const bf16* pA = &lA[bc_][0];
    const bf16* pB = &lB[bc_][0];
    short8 af[4], bfv[4];
#pragma unroll
    for (int mi = 0; mi < 4; ++mi)
      af[mi] = *(const short8*)&pA[(wrow + mi * 16 + fr) * 32 + fq * 8];
#pragma unroll
    for (int ni = 0; ni < 4; ++ni)
      bfv[ni] = *(const short8*)&pB[(wcol + ni * 16 + fr) * 32 + fq * 8];
    __builtin_amdgcn_s_setprio(1);
#pragma unroll
    for (int mi = 0; mi < 4; ++mi)
#pragma unroll
      for (int ni = 0; ni < 4; ++ni)
        acc[mi][ni] = mfma16(bfv[ni], af[mi], acc[mi][ni]);  // transposed
    __builtin_amdgcn_s_setprio(0);
    bc_ = (bc_ == 2) ? 0 : bc_ + 1;
    bs_ = (bs_ == 2) ? 0 : bs_ + 1;
  }
#undef GSTAGE

  if (epi == 0) {
#pragma unroll
    for (int mi = 0; mi < 4; ++mi)
#pragma unroll
      for (int ni = 0; ni < 4; ++ni) {
        int t = m0 + wrow + mi * 16 + fr;          // lane-fixed token
        int e4 = n0 + wcol + ni * 16 + fq * 4;     // 4 consecutive cols
        int sect = e4 >> 10, eh = (e4 >> 6) & 15, dh = e4 & 63;
        int b = t >> 11, tt = t & 2047;
        f32x4 a = acc[mi][ni];
        if (sect < 2) {
          size_t idx = (((size_t)b * 16 + eh) * 2048 + tt) * 64 + dh;
          float sc = (sect == 0) ? SCALE_Q : 1.f;  // pre-scale Q
          u32x2 ov;
          ov[0] = cvtpk(a[0] * sc, a[1] * sc);
          ov[1] = cvtpk(a[2] * sc, a[3] * sc);
          bf16* dst = (sect == 0) ? Qb : Kb;
          *(u32x2*)(dst + idx) = ov;
        } else {
          // V directly transposed: Vt[bh][d][t], 16-lane-contiguous 2B stores
          size_t vb = ((size_t)((b << 4) + eh) * 64 + dh) * 2048 + tt;
          unsigned p0 = cvtpk(a[0], a[1]);
          unsigned p1 = cvtpk(a[2], a[3]);
          unsigned short* vp = (unsigned short*)Vt;
          vp[vb] = (unsigned short)p0;
          vp[vb + 2048] = (unsigned short)(p0 >> 16);
          vp[vb + 4096] = (unsigned short)p1;
          vp[vb + 6144] = (unsigned short)(p1 >> 16);
        }
      }
  } else {
#pragma unroll
    for (int mi = 0; mi < 4; ++mi)
#pragma unroll
      for (int ni = 0; ni < 4; ++ni) {
        int t = m0 + wrow + mi * 16 + fr;
        int e4 = n0 + wcol + ni * 16 + fq * 4;
        f32x4 bv = *(const f32x4*)(bias + e4);
        f32x4 a = acc[mi][ni];
        f32x4 o = {a[0] + bv[0], a[1] + bv[1], a[2] + bv[2], a[3] + bv[3]};
        *(f32x4*)(Out + (size_t)t * N + e4) = o;
      }
  }
}

// ---------------- flash attention: KVBLK=128, bias-seeded T15 overlap -------
// 256 thr = 4 waves, wave owns 32 q-rows; grid 512 (XCD-swizzled).
// K 2-buf (static via unroll-2) + V 3-buf (rotating LDS offsets) = 80KB.
// Per iter: one raw barrier + vmcnt(0) (stage a full tile old = free);
// bias(t+1) loaded DIRECTLY into next s-set as QK's C-seed (no bias regs, no
// bias adds); stage(t+2) issued after bias so the compiler's bias wait
// (vmcnt(8)) leaves the stage in flight; then per-kb interleave
// {QK(t+1) MFMA || exp(t) trans || PV(t) MFMA} — three independent streams.
// Fixed softmax max (-16 baked into bias). P in-register (cvt_pk+permlane).
__global__ __launch_bounds__(256, 2) void k_attn(
    const bf16* __restrict__ Qb, const bf16* __restrict__ Kb,
    const bf16* __restrict__ Vt, const float* __restrict__ relpf,
    bf16* __restrict__ AO) {
  __shared__ bf16 lK[2][8192];   // [128 kv][64 d], chunk-XOR-swizzled
  __shared__ bf16 lV[3 * 8192];  // 3 x [64 d][128 kv], chunk-XOR-swizzled

  const int id = blockIdx.x;            // 0..511
  const int xcd = id & 7, j = id >> 3;  // j: 0..63
  const int bh = xcd * 4 + (j >> 4), qt = j & 15;
  const int h = bh & 15, b = bh >> 4;
  const int tid = threadIdx.x, w = tid >> 6, l = tid & 63;
  const int r32 = l & 31, hl = l >> 5, rs7 = r32 & 7;
  const int q0w = qt * 128 + w * 32;

  const bf16* Kbh = Kb + (size_t)bh * 2048 * 64;
  const bf16* Vbh = Vt + (size_t)bh * 64 * 2048;
  // staging: 1024 chunks of 16B each for K and V; thread covers 4 of each
  const bf16* Ks[4];
  const bf16* Vs[4];
#pragma unroll
  for (int s = 0; s < 4; ++s) {
    int c = tid + 256 * s;
    int kr = c >> 3, kc = (c & 7) ^ (kr & 7);
    Ks[s] = Kbh + (size_t)kr * 64 + kc * 8;
    int vr = c >> 4, vc = (c & 15) ^ (vr & 7);
    Vs[s] = Vbh + (size_t)vr * 2048 + vc * 8;
  }

#define STAGEK(KT, BI)                                                         \
  do {                                                                         \
    _Pragma("unroll") for (int s_ = 0; s_ < 4; ++s_)                           \
        GLD_LDS16(Ks[s_] + (size_t)(KT) * 64,                                  \
                  &lK[BI][(tid + 256 * s_) * 8]);                              \
  } while (0)
#define STAGEV(KT, OFF)                                                        \
  do {                                                                         \
    _Pragma("unroll") for (int s_ = 0; s_ < 4; ++s_)                           \
        GLD_LDS16(Vs[s_] + (KT), &lV[(OFF) + (tid + 256 * s_) * 8]);           \
  } while (0)

  // Q as B-operand: col q = r32, k(d) = ks*16 + hl*8 + j  (pre-scaled)
  const bf16* Qp = Qb + ((size_t)bh * 2048 + q0w + r32) * 64;
  short8 qf[4];
#pragma unroll
  for (int ks = 0; ks < 4; ++ks)
    qf[ks] = *(const short8*)(Qp + ks * 16 + hl * 8);

  // bias: idx = kv - q + 2047; kv = kt + kb*32 + (reg&3) + 8*(reg>>2) + 4*hl
  // reg groups of 4 contiguous -> dwordx4; has -16 (fixed max) and log2e baked
  const float* bp = relpf + h * 4096 + (2047 + 4 * hl - q0w - r32);

  float llane = 0.f;
  f32x16 o0 = {}, o1 = {};
  f32x16 sA[4], sB[4];
  unsigned vOff0 = 0, vOff1 = 8192, vOff2 = 16384;  // rotating V slots

  // prologue: bias(0)->sA seed; stage tiles 0,1; QK(0) -> sA
#pragma unroll
  for (int kb = 0; kb < 4; ++kb)
#pragma unroll
    for (int g = 0; g < 4; ++g) {
      f32x4u v_ = *(const f32x4u*)(bp + kb * 32 + 8 * g);
      sA[kb][4 * g + 0] = v_[0];
      sA[kb][4 * g + 1] = v_[1];
      sA[kb][4 * g + 2] = v_[2];
      sA[kb][4 * g + 3] = v_[3];
    }
  __builtin_amdgcn_sched_barrier(0);
  STAGEK(0, 0);
  STAGEV(0, 0);
  STAGEK(128, 1);
  STAGEV(128, 8192);
  __builtin_amdgcn_sched_barrier(0);
  asm volatile("s_waitcnt vmcnt(12)" ::: "memory");  // bias(0)+K(0) done
  __builtin_amdgcn_s_barrier();
  __builtin_amdgcn_sched_barrier(0);
  __builtin_amdgcn_s_setprio(1);
#pragma unroll
  for (int kb = 0; kb < 4; ++kb)
#pragma unroll
    for (int ks = 0; ks < 4; ++ks) {
      short8 kf = *(const short8*)&lK[0][(kb * 32 + r32) * 64 +
                                         (((2 * ks + hl) ^ rs7) * 8)];
      sA[kb] = mfma32(kf, qf[ks], sA[kb]);
    }
  __builtin_amdgcn_s_setprio(0);

#define ITER(T, SC, SN, DN)                                                    \
  do {                                                                         \
    const int t_ = (T);                                                        \
    asm volatile("s_waitcnt vmcnt(0)" ::: "memory"); /* stage(t+1) done */     \
    __builtin_amdgcn_s_barrier();                                              \
    __builtin_amdgcn_sched_barrier(0);                                         \
    if (DN) { /* bias(t+1) seed into SN, THEN stage(t+2) */                    \
      _Pragma("unroll") for (int kb = 0; kb < 4; ++kb)                         \
          _Pragma("unroll") for (int g = 0; g < 4; ++g) {                      \
        f32x4u v_ = *(const f32x4u*)(bp + (t_ + 1) * 128 + kb * 32 + 8 * g);   \
        SN[kb][4 * g + 0] = v_[0];                                             \
        SN[kb][4 * g + 1] = v_[1];                                             \
        SN[kb][4 * g + 2] = v_[2];                                             \
        SN[kb][4 * g + 3] = v_[3];                                             \
      }                                                                        \
      __builtin_amdgcn_sched_barrier(0);                                       \
      {                                                                        \
        int ts_ = (t_ + 2 > 15) ? 15 : t_ + 2;                                 \
        STAGEK(ts_ * 128, (t_ & 1));                                           \
        STAGEV(ts_ * 128, vOff2);                                              \
      }                                                                        \
      __builtin_amdgcn_sched_barrier(0);                                       \
    }                                                                          \
    float ra0 = 0.f, ra1 = 0.f, ra2 = 0.f, ra3 = 0.f;                          \
    _Pragma("unroll") for (int kb = 0; kb < 4; ++kb) {                         \
      if (DN) { /* QK(t+1, kb): MFMA stream into SN */                         \
        __builtin_amdgcn_s_setprio(1);                                         \
        _Pragma("unroll") for (int ks = 0; ks < 4; ++ks) {                     \
          short8 kf = *(const short8*)&lK[(t_ + 1) & 1]                        \
              [(kb * 32 + r32) * 64 + (((2 * ks + hl) ^ rs7) * 8)];            \
          SN[kb] = mfma32(kf, qf[ks], SN[kb]);                                 \
        }                                                                      \
        __builtin_amdgcn_s_setprio(0);                                         \
      }                                                                        \
      /* exp(t, kb): trans/VALU stream (bias already inside SC) */             \
      _Pragma("unroll") for (int reg = 0; reg < 16; ++reg) {                   \
        float e_ = fexp2(SC[kb][reg]);                                         \
        SC[kb][reg] = e_;                                                      \
        if ((reg & 3) == 0) ra0 += e_;                                         \
        else if ((reg & 3) == 1) ra1 += e_;                                    \
        else if ((reg & 3) == 2) ra2 += e_;                                    \
        else ra3 += e_;                                                        \
      }                                                                        \
      /* PV(t, kb): MFMA stream into o */                                      \
      _Pragma("unroll") for (int kh = 0; kh < 2; ++kh) {                       \
        const int e = kh * 8;                                                  \
        unsigned a0 = cvtpk(SC[kb][e + 0], SC[kb][e + 1]);                     \
        unsigned a1 = cvtpk(SC[kb][e + 2], SC[kb][e + 3]);                     \
        unsigned b0 = cvtpk(SC[kb][e + 4], SC[kb][e + 5]);                     \
        unsigned b1 = cvtpk(SC[kb][e + 6], SC[kb][e + 7]);                     \
        PLSWAP(a0, b0); /* distinct values: no coalescing hazard */            \
        PLSWAP(a1, b1);                                                        \
        u32x4 pw = {a0, a1, b0, b1};                                           \
        short8 pf = __builtin_bit_cast(short8, pw);                            \
        const int ks = kb * 2 + kh;                                            \
        const int cc = ((2 * ks + hl) ^ rs7) * 8;                              \
        short8 v0 = *(const short8*)&lV[vOff0 + r32 * 128 + cc];               \
        short8 v1 = *(const short8*)&lV[vOff0 + (32 + r32) * 128 + cc];        \
        __builtin_amdgcn_s_setprio(1);                                         \
        o0 = mfma32(v0, pf, o0);                                               \
        o1 = mfma32(v1, pf, o1);                                               \
        __builtin_amdgcn_s_setprio(0);                                         \
      }                                                                        \
    }                                                                          \
    llane += (ra0 + ra1) + (ra2 + ra3);                                        \
    { unsigned tmp_ = vOff0; vOff0 = vOff1; vOff1 = vOff2; vOff2 = tmp_; }     \
  } while (0)

  for (int tt = 0; tt < 7; ++tt) {  // t = 0..13; static sA/sB swap
    ITER(2 * tt, sA, sB, 1);
    ITER(2 * tt + 1, sB, sA, 1);
  }
  ITER(14, sA, sB, 1);
  ITER(15, sB, sA, 0);  // tail: no QK(16), no bias, no stage
#undef ITER
#undef STAGEK
#undef STAGEV

  // lane: q = r32; o[db][reg] = O^T[d = db*32 + (reg&3)+8*(reg>>2)+4*hl][q]
  float lsum = llane + __shfl_xor(llane, 32);  // pair-combine once
  float rin = 1.f / lsum;
  bf16* aor = AO + ((size_t)(b * 2048 + q0w + r32)) * 1024 + h * 64 + hl * 4;
#pragma unroll
  for (int rg = 0; rg < 4; ++rg) {
    u32x2 ov0, ov1;
    ov0[0] = cvtpk(o0[4 * rg + 0] * rin, o0[4 * rg + 1] * rin);
    ov0[1] = cvtpk(o0[4 * rg + 2] * rin, o0[4 * rg + 3] * rin);
    *(u32x2*)(aor + rg * 8) = ov0;
    ov1[0] = cvtpk(o1[4 * rg + 0] * rin, o1[4 * rg + 1] * rin);
    ov1[1] = cvtpk(o1[4 * rg + 2] * rin, o1[4 * rg + 3] * rin);
    *(u32x2*)(aor + 32 + rg * 8) = ov1;
  }
}

// ---------------------------------------------------------------------------
extern "C" void kernel_launch(void* const* d_in, const int* in_sizes, int n_in,
                              void* d_out, int out_size, void* d_ws,
                              size_t ws_size, hipStream_t stream) {
  const float* x = (const float*)d_in[0];     // [2,2048,1024]
  const float* Wqkv = (const float*)d_in[1];  // [3072,1024]
  const float* Wout = (const float*)d_in[2];  // [1024,1024]
  const float* bout = (const float*)d_in[3];  // [1024]
  const float* rel = (const float*)d_in[4];   // [2049,16]
  float* out = (float*)d_out;

  char* p = (char*)d_ws;
  bf16* xb  = (bf16*)(p);                      // 8 MB  [4096][1024]
  bf16* wqb = (bf16*)(p + (8ull << 20));       // 6 MB  [3072][1024]
  bf16* wob = (bf16*)(p + (14ull << 20));      // 2 MB  [1024][1024]
  bf16* Qb  = (bf16*)(p + (16ull << 20));      // 8 MB  [32][2048][64]
  bf16* Kb  = (bf16*)(p + (24ull << 20));      // 8 MB
  bf16* Vtr = (bf16*)(p + (32ull << 20));      // 8 MB  [32][64][2048]
  bf16* aob = (bf16*)(p + (40ull << 20));      // 8 MB  [4096][1024]
  float* relpf = (float*)(p + (48ull << 20));  // 256 KB [16][4096] f32

  k_pre<<<8256, 256, 0, stream>>>(x, Wqkv, Wout, rel, xb, wqb, wob, relpf);
  k_gemm<<<dim3(32, 24), 256, 0, stream>>>(xb, wqb, 4096, 3072, 1024, 0,
                                           Qb, Kb, Vtr, nullptr, nullptr);
  k_attn<<<512, 256, 0, stream>>>(Qb, Kb, Vtr, relpf, aob);
  k_gemm<<<dim3(32, 8), 256, 0, stream>>>(aob, wob, 4096, 1024, 1024, 1,
                                          nullptr, nullptr, nullptr, out, bout);
}

// Round 15
// 121.221 us; speedup vs baseline: 1.7406x; 1.0068x over previous
//
#include <hip/hip_runtime.h>
#include <hip/hip_bf16.h>

typedef __attribute__((ext_vector_type(8))) short short8;
typedef __attribute__((ext_vector_type(4))) float f32x4;
typedef __attribute__((ext_vector_type(16))) float f32x16;
typedef float f32x4u __attribute__((ext_vector_type(4), aligned(4)));
typedef __attribute__((ext_vector_type(4))) unsigned short u16x4;
typedef __attribute__((ext_vector_type(2))) unsigned int u32x2;
typedef __attribute__((ext_vector_type(4))) unsigned int u32x4;
typedef __hip_bfloat16 bf16;

#define SCALE_Q 0.18033688f  // d^-0.5 * log2(e)

#define GLD_LDS16(g, l) __builtin_amdgcn_global_load_lds(                      \
    (const __attribute__((address_space(1))) void*)(g),                        \
    (__attribute__((address_space(3))) void*)(l), 16, 0, 0)

static __device__ __forceinline__ f32x4 mfma16(short8 a, short8 b, f32x4 c) {
  return __builtin_amdgcn_mfma_f32_16x16x32_bf16(a, b, c, 0, 0, 0);
}
static __device__ __forceinline__ f32x16 mfma32(short8 a, short8 b, f32x16 c) {
  return __builtin_amdgcn_mfma_f32_32x32x16_bf16(a, b, c, 0, 0, 0);
}

// packed f32x2 -> bf16x2 convert (single HW instr; no builtin on gfx950)
static __device__ __forceinline__ unsigned cvtpk(float lo, float hi) {
  unsigned r;
  asm("v_cvt_pk_bf16_f32 %0, %1, %2" : "=v"(r) : "v"(lo), "v"(hi));
  return r;
}

// raw v_exp_f32 (D = 2^S0): avoids libm's denormal-fixup sequence
static __device__ __forceinline__ float fexp2(float x) {
  float r;
  asm("v_exp_f32 %0, %1" : "=v"(r) : "v"(x));
  return r;
}

// vdst upper 32 lanes <-> vsrc lower 32 lanes. ONLY use with operands that
// hold DISTINCT values (identical-copy operands can be register-coalesced by
// the allocator -> self-swap bug; scalar reductions use __shfl_xor instead).
#define PLSWAP(a, b) asm("v_permlane32_swap_b32 %0, %1" : "+v"(a), "+v"(b))

// ---------------- fused preprocessing: 3x fp32->bf16 cvt + bias table -------
// blocks [0,4096): x->xb; [4096,7168): Wqkv->wqb; [7168,8192): Wout->wob;
// [8192,8256): relpf[h][i] = rel[clamp(i-2047,±1024)+1024][h]*log2(e) - 16
// (fixed softmax max baked in; scores bounded, bf16 keeps relative precision)
__global__ __launch_bounds__(256) void k_pre(
    const float* __restrict__ x, const float* __restrict__ Wqkv,
    const float* __restrict__ Wout, const float* __restrict__ rel,
    bf16* __restrict__ xb, bf16* __restrict__ wqb, bf16* __restrict__ wob,
    float* __restrict__ relpf) {
  int bid = blockIdx.x;
  if (bid < 8192) {
    const float* in;
    bf16* out;
    long i;
    if (bid < 4096) {
      in = x; out = xb; i = (long)bid * 256 + threadIdx.x;
    } else if (bid < 7168) {
      in = Wqkv; out = wqb; i = (long)(bid - 4096) * 256 + threadIdx.x;
    } else {
      in = Wout; out = wob; i = (long)(bid - 7168) * 256 + threadIdx.x;
    }
    f32x4 v = *(const f32x4*)(in + i * 4);
    u16x4 o;
#pragma unroll
    for (int j = 0; j < 4; ++j)
      o[j] = __builtin_bit_cast(unsigned short, __float2bfloat16(v[j]));
    *(u16x4*)((unsigned short*)out + i * 4) = o;
  } else {
    int base = (bid - 8192) * 1024 + threadIdx.x;
#pragma unroll
    for (int k = 0; k < 4; ++k) {
      int i = base + k * 256;  // 0..65535
      int h = i >> 12, ii = i & 4095;
      int dd = ii - 2047;
      dd = dd < -1024 ? -1024 : (dd > 1024 ? 1024 : dd);
      relpf[i] = rel[(size_t)(dd + 1024) * 16 + h] * 1.44269504f - 16.0f;
    }
  }
}

// ---------------- 128x128 bf16 GEMM, 3-buf counted-vmcnt pipeline -----------
// B stored [N][K]. mfma operands SWAPPED (bfv, af) -> lane holds 4 consecutive
// N-columns. Single raw barrier per K-step + s_waitcnt vmcnt(4).
// epi==0: scatter Q/K [bh][2048][64] (Q pre-scaled), V DIRECTLY TRANSPOSED
//         into Vt [bh][64][2048].
// epi==1: fp32 out[t*N+e] = acc + bias[e], 16B stores.
__global__ __launch_bounds__(256, 3) void k_gemm(
    const bf16* __restrict__ A, const bf16* __restrict__ B,
    int M, int N, int K, int epi,
    bf16* __restrict__ Qb, bf16* __restrict__ Kb, bf16* __restrict__ Vt,
    float* __restrict__ Out, const float* __restrict__ bias) {
  __shared__ bf16 lA[3][4096];  // 3 x (128 x 32)
  __shared__ bf16 lB[3][4096];
  const int tid = threadIdx.x, w = tid >> 6, l = tid & 63;
  const int m0 = blockIdx.x * 128, n0 = blockIdx.y * 128;
  const int wrow = (w >> 1) * 64, wcol = (w & 1) * 64;
  const int fr = l & 15, fq = l >> 4;
  f32x4 acc[4][4] = {};
  const int c0 = w * 64 + l, c1 = c0 + 256;  // 16B chunk ids
  const bf16* Ag0 = A + (size_t)(m0 + (c0 >> 2)) * K + (c0 & 3) * 8;
  const bf16* Ag1 = A + (size_t)(m0 + (c1 >> 2)) * K + (c1 & 3) * 8;
  const bf16* Bg0 = B + (size_t)(n0 + (c0 >> 2)) * K + (c0 & 3) * 8;
  const bf16* Bg1 = B + (size_t)(n0 + (c1 >> 2)) * K + (c1 & 3) * 8;
  bf16* lA0 = &lA[0][w * 512];
  bf16* lA1 = &lA[0][2048 + w * 512];
  bf16* lB0 = &lB[0][w * 512];
  bf16* lB1 = &lB[0][2048 + w * 512];

#define GSTAGE(T, BI)                                                          \
  do {                                                                         \
    const int ko_ = (T) * 32;                                                  \
    GLD_LDS16(Ag0 + ko_, lA0 + (BI) * 4096);                                   \
    GLD_LDS16(Ag1 + ko_, lA1 + (BI) * 4096);                                   \
    GLD_LDS16(Bg0 + ko_, lB0 + (BI) * 4096);                                   \
    GLD_LDS16(Bg1 + ko_, lB1 + (BI) * 4096);                                   \
  } while (0)

  const int nk = K >> 5;
  GSTAGE(0, 0);
  __builtin_amdgcn_sched_barrier(0);
  GSTAGE(1, 1);
  __builtin_amdgcn_sched_barrier(0);

  int bc_ = 0, bs_ = 2;
  for (int t = 0; t < nk; ++t) {
    asm volatile("s_waitcnt vmcnt(4)" ::: "memory");  // stage(t) done
    __builtin_amdgcn_s_barrier();                     // all waves' stage(t)
    __builtin_amdgcn_sched_barrier(0);
    int tt = (t + 2 < nk) ? t + 2 : nk - 1;  // clamp keeps count invariant
    GSTAGE(tt, bs_);
    __builtin_amdgcn_sched_barrier(0);
    const bf16* pA = &lA[bc_][0];
    const bf16* pB = &lB[bc_][0];
    short8 af[4], bfv[4];
#pragma unroll
    for (int mi = 0; mi < 4; ++mi)
      af[mi] = *(const short8*)&pA[(wrow + mi * 16 + fr) * 32 + fq * 8];
#pragma unroll
    for (int ni = 0; ni < 4; ++ni)
      bfv[ni] = *(const short8*)&pB[(wcol + ni * 16 + fr) * 32 + fq * 8];
    __builtin_amdgcn_s_setprio(1);
#pragma unroll
    for (int mi = 0; mi < 4; ++mi)
#pragma unroll
      for (int ni = 0; ni < 4; ++ni)
        acc[mi][ni] = mfma16(bfv[ni], af[mi], acc[mi][ni]);  // transposed
    __builtin_amdgcn_s_setprio(0);
    bc_ = (bc_ == 2) ? 0 : bc_ + 1;
    bs_ = (bs_ == 2) ? 0 : bs_ + 1;
  }
#undef GSTAGE

  if (epi == 0) {
#pragma unroll
    for (int mi = 0; mi < 4; ++mi)
#pragma unroll
      for (int ni = 0; ni < 4; ++ni) {
        int t = m0 + wrow + mi * 16 + fr;          // lane-fixed token
        int e4 = n0 + wcol + ni * 16 + fq * 4;     // 4 consecutive cols
        int sect = e4 >> 10, eh = (e4 >> 6) & 15, dh = e4 & 63;
        int b = t >> 11, tt = t & 2047;
        f32x4 a = acc[mi][ni];
        if (sect < 2) {
          size_t idx = (((size_t)b * 16 + eh) * 2048 + tt) * 64 + dh;
          float sc = (sect == 0) ? SCALE_Q : 1.f;  // pre-scale Q
          u32x2 ov;
          ov[0] = cvtpk(a[0] * sc, a[1] * sc);
          ov[1] = cvtpk(a[2] * sc, a[3] * sc);
          bf16* dst = (sect == 0) ? Qb : Kb;
          *(u32x2*)(dst + idx) = ov;
        } else {
          // V directly transposed: Vt[bh][d][t], 16-lane-contiguous 2B stores
          size_t vb = ((size_t)((b << 4) + eh) * 64 + dh) * 2048 + tt;
          unsigned p0 = cvtpk(a[0], a[1]);
          unsigned p1 = cvtpk(a[2], a[3]);
          unsigned short* vp = (unsigned short*)Vt;
          vp[vb] = (unsigned short)p0;
          vp[vb + 2048] = (unsigned short)(p0 >> 16);
          vp[vb + 4096] = (unsigned short)p1;
          vp[vb + 6144] = (unsigned short)(p1 >> 16);
        }
      }
  } else {
#pragma unroll
    for (int mi = 0; mi < 4; ++mi)
#pragma unroll
      for (int ni = 0; ni < 4; ++ni) {
        int t = m0 + wrow + mi * 16 + fr;
        int e4 = n0 + wcol + ni * 16 + fq * 4;
        f32x4 bv = *(const f32x4*)(bias + e4);
        f32x4 a = acc[mi][ni];
        f32x4 o = {a[0] + bv[0], a[1] + bv[1], a[2] + bv[2], a[3] + bv[3]};
        *(f32x4*)(Out + (size_t)t * N + e4) = o;
      }
  }
}

// ---------------- flash attention: KVBLK=128, T14 reg-staged write-late -----
// 256 thr = 4 waves, wave owns 32 q-rows; grid 512 (XCD-swizzled).
// Staging via registers (T14 async-STAGE split): global loads for tile t+1
// issued right after the bias loads (latency hides under QK+exp); the
// ds_write_b128s land AFTER PV, in the tile-end window where the LDS pipe is
// idle — removes the mid-tile DMA-write vs ds_read collision of
// global_load_lds. Read side & data layout identical to the DMA version
// (same pre-swizzled sources, same linear LDS dest). Sync: lgkmcnt(0) + raw
// barrier per tile (writes target buf (t+1)&1 whose readers passed the
// top-of-t barrier). Fixed softmax max (-16 baked into bias table); P built
// in-register (cvt_pk + permlane swap).
__global__ __launch_bounds__(256, 2) void k_attn(
    const bf16* __restrict__ Qb, const bf16* __restrict__ Kb,
    const bf16* __restrict__ Vt, const float* __restrict__ relpf,
    bf16* __restrict__ AO) {
  __shared__ bf16 lK[2][8192];  // [128 kv][64 d], chunk-XOR-swizzled
  __shared__ bf16 lV[2][8192];  // [64 d][128 kv], chunk-XOR-swizzled

  const int id = blockIdx.x;            // 0..511
  const int xcd = id & 7, j = id >> 3;  // j: 0..63
  const int bh = xcd * 4 + (j >> 4), qt = j & 15;
  const int h = bh & 15, b = bh >> 4;
  const int tid = threadIdx.x, w = tid >> 6, l = tid & 63;
  const int r32 = l & 31, hl = l >> 5, rs7 = r32 & 7;
  const int q0w = qt * 128 + w * 32;

  const bf16* Kbh = Kb + (size_t)bh * 2048 * 64;
  const bf16* Vbh = Vt + (size_t)bh * 64 * 2048;
  // staging geometry: 1024 chunks of 16B each for K and V; thread covers 4
  // of each. Source pre-swizzled, LDS dest linear (identical to DMA layout).
  const bf16* Ks[4];
  const bf16* Vs[4];
#pragma unroll
  for (int s = 0; s < 4; ++s) {
    int c = tid + 256 * s;
    int kr = c >> 3, kc = (c & 7) ^ (kr & 7);
    Ks[s] = Kbh + (size_t)kr * 64 + kc * 8;
    int vr = c >> 4, vc = (c & 15) ^ (vr & 7);
    Vs[s] = Vbh + (size_t)vr * 2048 + vc * 8;
  }

  u32x4 kreg[4], vreg[4];  // in-flight staging registers (32 VGPR)

#define LOADKV(KT)                                                             \
  do {                                                                         \
    _Pragma("unroll") for (int s_ = 0; s_ < 4; ++s_) {                         \
      kreg[s_] = *(const u32x4*)(Ks[s_] + (size_t)(KT) * 64);                  \
      vreg[s_] = *(const u32x4*)(Vs[s_] + (KT));                               \
    }                                                                          \
  } while (0)
#define WRITEKV(BI)                                                            \
  do {                                                                         \
    _Pragma("unroll") for (int s_ = 0; s_ < 4; ++s_) {                         \
      *(u32x4*)&lK[BI][(tid + 256 * s_) * 8] = kreg[s_];                       \
      *(u32x4*)&lV[BI][(tid + 256 * s_) * 8] = vreg[s_];                       \
    }                                                                          \
  } while (0)

  // Q as B-operand: col q = r32, k(d) = ks*16 + hl*8 + j  (pre-scaled)
  const bf16* Qp = Qb + ((size_t)bh * 2048 + q0w + r32) * 64;
  short8 qf[4];
#pragma unroll
  for (int ks = 0; ks < 4; ++ks)
    qf[ks] = *(const short8*)(Qp + ks * 16 + hl * 8);

  // bias: idx = kv - q + 2047; kv = kt + kb*32 + (reg&3) + 8*(reg>>2) + 4*hl
  const float* bp = relpf + h * 4096 + (2047 + 4 * hl - q0w - r32);

  float llane = 0.f;
  f32x16 o0 = {}, o1 = {};

  // prologue: stage tile 0 through regs
  LOADKV(0);
  WRITEKV(0);  // compiler inserts the vmcnt waits for kreg/vreg uses

  int cur = 0;
  for (int t = 0; t < 16; ++t) {
    const int kt = t * 128;
    asm volatile("s_waitcnt lgkmcnt(0)" ::: "memory");  // my ds_writes done
    __builtin_amdgcn_s_barrier();  // all waves' writes visible, reads done
    __builtin_amdgcn_sched_barrier(0);
    // bias for this tile first (older in queue), then next tile's kv loads
    // (newest -> exp's implicit bias wait leaves them in flight)
    f32x16 bc[4];
#pragma unroll
    for (int kb = 0; kb < 4; ++kb)
#pragma unroll
      for (int g = 0; g < 4; ++g) {
        f32x4u v = *(const f32x4u*)(bp + kt + kb * 32 + 8 * g);
#pragma unroll
        for (int e = 0; e < 4; ++e) bc[kb][g * 4 + e] = v[e];
      }
    __builtin_amdgcn_sched_barrier(0);
    if (t < 15) LOADKV(kt + 128);  // -> regs; latency hides under QK+exp
    __builtin_amdgcn_sched_barrier(0);
    const bf16* lKc = &lK[cur][0];
    const bf16* lVc = &lV[cur][0];
    // ---- S^T = K Q^T : 4 kv-blocks of 32
    f32x16 s[4] = {};
    __builtin_amdgcn_s_setprio(1);
#pragma unroll
    for (int kb = 0; kb < 4; ++kb)
#pragma unroll
      for (int ks = 0; ks < 4; ++ks) {
        short8 kf = *(const short8*)&lKc[(kb * 32 + r32) * 64 +
                                         (((2 * ks + hl) ^ rs7) * 8)];
        s[kb] = mfma32(kf, qf[ks], s[kb]);
      }
    __builtin_amdgcn_s_setprio(0);
    // ---- fixed-max softmax: P = exp2(s + bias'), bias' has -16 baked in
    float ra[4] = {0.f, 0.f, 0.f, 0.f};
#pragma unroll
    for (int kb = 0; kb < 4; ++kb)
#pragma unroll
      for (int reg = 0; reg < 16; ++reg) {
        float e = fexp2(s[kb][reg] + bc[kb][reg]);
        s[kb][reg] = e;
        ra[reg & 3] += e;
      }
    llane += (ra[0] + ra[1]) + (ra[2] + ra[3]);
    // ---- P-frags in-register + PV: O^T[d][q] += V^T P
#pragma unroll
    for (int kb = 0; kb < 4; ++kb) {
#pragma unroll
      for (int kh = 0; kh < 2; ++kh) {
        const int e = kh * 8;
        unsigned a0 = cvtpk(s[kb][e + 0], s[kb][e + 1]);
        unsigned a1 = cvtpk(s[kb][e + 2], s[kb][e + 3]);
        unsigned b0 = cvtpk(s[kb][e + 4], s[kb][e + 5]);
        unsigned b1 = cvtpk(s[kb][e + 6], s[kb][e + 7]);
        PLSWAP(a0, b0);  // distinct values: no coalescing hazard
        PLSWAP(a1, b1);
        u32x4 pw = {a0, a1, b0, b1};
        short8 pf = __builtin_bit_cast(short8, pw);
        const int ks = kb * 2 + kh;
        const int cc = ((2 * ks + hl) ^ rs7) * 8;
        short8 v0 = *(const short8*)&lVc[r32 * 128 + cc];
        short8 v1 = *(const short8*)&lVc[(32 + r32) * 128 + cc];
        __builtin_amdgcn_s_setprio(1);
        o0 = mfma32(v0, pf, o0);
        o1 = mfma32(v1, pf, o1);
        __builtin_amdgcn_s_setprio(0);
      }
    }
    __builtin_amdgcn_sched_barrier(0);
    if (t < 15) WRITEKV(cur ^ 1);  // write-late: LDS pipe idle post-PV
    cur ^= 1;
  }
#undef LOADKV
#undef WRITEKV

  // lane: q = r32; o[db][reg] = O^T[d = db*32 + (reg&3)+8*(reg>>2)+4*hl][q]
  float lsum = llane + __shfl_xor(llane, 32);  // pair-combine once
  float rin = 1.f / lsum;
  bf16* aor = AO + ((size_t)(b * 2048 + q0w + r32)) * 1024 + h * 64 + hl * 4;
#pragma unroll
  for (int rg = 0; rg < 4; ++rg) {
    u32x2 ov0, ov1;
    ov0[0] = cvtpk(o0[4 * rg + 0] * rin, o0[4 * rg + 1] * rin);
    ov0[1] = cvtpk(o0[4 * rg + 2] * rin, o0[4 * rg + 3] * rin);
    *(u32x2*)(aor + rg * 8) = ov0;
    ov1[0] = cvtpk(o1[4 * rg + 0] * rin, o1[4 * rg + 1] * rin);
    ov1[1] = cvtpk(o1[4 * rg + 2] * rin, o1[4 * rg + 3] * rin);
    *(u32x2*)(aor + 32 + rg * 8) = ov1;
  }
}

// ---------------------------------------------------------------------------
extern "C" void kernel_launch(void* const* d_in, const int* in_sizes, int n_in,
                              void* d_out, int out_size, void* d_ws,
                              size_t ws_size, hipStream_t stream) {
  const float* x = (const float*)d_in[0];     // [2,2048,1024]
  const float* Wqkv = (const float*)d_in[1];  // [3072,1024]
  const float* Wout = (const float*)d_in[2];  // [1024,1024]
  const float* bout = (const float*)d_in[3];  // [1024]
  const float* rel = (const float*)d_in[4];   // [2049,16]
  float* out = (float*)d_out;

  char* p = (char*)d_ws;
  bf16* xb  = (bf16*)(p);                      // 8 MB  [4096][1024]
  bf16* wqb = (bf16*)(p + (8ull << 20));       // 6 MB  [3072][1024]
  bf16* wob = (bf16*)(p + (14ull << 20));      // 2 MB  [1024][1024]
  bf16* Qb  = (bf16*)(p + (16ull << 20));      // 8 MB  [32][2048][64]
  bf16* Kb  = (bf16*)(p + (24ull << 20));      // 8 MB
  bf16* Vtr = (bf16*)(p + (32ull << 20));      // 8 MB  [32][64][2048]
  bf16* aob = (bf16*)(p + (40ull << 20));      // 8 MB  [4096][1024]
  float* relpf = (float*)(p + (48ull << 20));  // 256 KB [16][4096] f32

  k_pre<<<8256, 256, 0, stream>>>(x, Wqkv, Wout, rel, xb, wqb, wob, relpf);
  k_gemm<<<dim3(32, 24), 256, 0, stream>>>(xb, wqb, 4096, 3072, 1024, 0,
                                           Qb, Kb, Vtr, nullptr, nullptr);
  k_attn<<<512, 256, 0, stream>>>(Qb, Kb, Vtr, relpf, aob);
  k_gemm<<<dim3(32, 8), 256, 0, stream>>>(aob, wob, 4096, 1024, 1024, 1,
                                          nullptr, nullptr, nullptr, out, bout);
}

// Round 17
// 120.559 us; speedup vs baseline: 1.7502x; 1.0055x over previous
//
#include <hip/hip_runtime.h>
#include <hip/hip_bf16.h>

typedef __attribute__((ext_vector_type(8))) short short8;
typedef __attribute__((ext_vector_type(4))) float f32x4;
typedef __attribute__((ext_vector_type(16))) float f32x16;
typedef float f32x4u __attribute__((ext_vector_type(4), aligned(4)));
typedef __attribute__((ext_vector_type(4))) unsigned short u16x4;
typedef __attribute__((ext_vector_type(2))) unsigned int u32x2;
typedef __attribute__((ext_vector_type(4))) unsigned int u32x4;
typedef __hip_bfloat16 bf16;

#define SCALE_Q 0.18033688f  // d^-0.5 * log2(e)

#define GLD_LDS16(g, l) __builtin_amdgcn_global_load_lds(                      \
    (const __attribute__((address_space(1))) void*)(g),                        \
    (__attribute__((address_space(3))) void*)(l), 16, 0, 0)

static __device__ __forceinline__ f32x4 mfma16(short8 a, short8 b, f32x4 c) {
  return __builtin_amdgcn_mfma_f32_16x16x32_bf16(a, b, c, 0, 0, 0);
}
static __device__ __forceinline__ f32x16 mfma32(short8 a, short8 b, f32x16 c) {
  return __builtin_amdgcn_mfma_f32_32x32x16_bf16(a, b, c, 0, 0, 0);
}

// packed f32x2 -> bf16x2 convert (single HW instr; no builtin on gfx950)
static __device__ __forceinline__ unsigned cvtpk(float lo, float hi) {
  unsigned r;
  asm("v_cvt_pk_bf16_f32 %0, %1, %2" : "=v"(r) : "v"(lo), "v"(hi));
  return r;
}

// raw v_exp_f32 (D = 2^S0): avoids libm's denormal-fixup sequence
static __device__ __forceinline__ float fexp2(float x) {
  float r;
  asm("v_exp_f32 %0, %1" : "=v"(r) : "v"(x));
  return r;
}

// vdst upper 32 lanes <-> vsrc lower 32 lanes. ONLY use with operands that
// hold DISTINCT values (identical-copy operands can be register-coalesced by
// the allocator -> self-swap bug; scalar reductions use __shfl_xor instead).
#define PLSWAP(a, b) asm("v_permlane32_swap_b32 %0, %1" : "+v"(a), "+v"(b))

// ---------------- fused preprocessing: 3x fp32->bf16 cvt + bias table -------
// 32B/thread cvt. blocks [0,2048): x->xb; [2048,3584): Wqkv->wqb;
// [3584,4096): Wout->wob; [4096,4160): relpf[h][i] =
// rel[clamp(i-2047,±1024)+1024][h]*log2(e) - 16 (fixed softmax max baked in;
// scores bounded, bf16 keeps relative precision)
__global__ __launch_bounds__(256) void k_pre(
    const float* __restrict__ x, const float* __restrict__ Wqkv,
    const float* __restrict__ Wout, const float* __restrict__ rel,
    bf16* __restrict__ xb, bf16* __restrict__ wqb, bf16* __restrict__ wob,
    float* __restrict__ relpf) {
  int bid = blockIdx.x;
  if (bid < 4096) {
    const float* in;
    bf16* out;
    long i;
    if (bid < 2048) {
      in = x; out = xb; i = (long)bid * 256 + threadIdx.x;
    } else if (bid < 3584) {
      in = Wqkv; out = wqb; i = (long)(bid - 2048) * 256 + threadIdx.x;
    } else {
      in = Wout; out = wob; i = (long)(bid - 3584) * 256 + threadIdx.x;
    }
    f32x4 v0 = *(const f32x4*)(in + i * 8);
    f32x4 v1 = *(const f32x4*)(in + i * 8 + 4);
    u32x4 o;
    o[0] = cvtpk(v0[0], v0[1]);
    o[1] = cvtpk(v0[2], v0[3]);
    o[2] = cvtpk(v1[0], v1[1]);
    o[3] = cvtpk(v1[2], v1[3]);
    *(u32x4*)((unsigned short*)out + i * 8) = o;
  } else {
    int base = (bid - 4096) * 1024 + threadIdx.x;
#pragma unroll
    for (int k = 0; k < 4; ++k) {
      int i = base + k * 256;  // 0..65535
      int h = i >> 12, ii = i & 4095;
      int dd = ii - 2047;
      dd = dd < -1024 ? -1024 : (dd > 1024 ? 1024 : dd);
      relpf[i] = rel[(size_t)(dd + 1024) * 16 + h] * 1.44269504f - 16.0f;
    }
  }
}

// ---------------- 128x128 bf16 GEMM, 3-buf counted-vmcnt pipeline -----------
// B stored [N][K]. mfma operands SWAPPED (bfv, af) -> lane holds 4 consecutive
// N-columns. Single raw barrier per K-step + s_waitcnt vmcnt(4).
// epi==0: scatter Q/K [bh][2048][64] (Q pre-scaled), V DIRECTLY TRANSPOSED
//         into Vt [bh][64][2048].
// epi==1: fp32 out[t*N+e] = acc + bias[e], 16B stores.
__global__ __launch_bounds__(256, 3) void k_gemm(
    const bf16* __restrict__ A, const bf16* __restrict__ B,
    int M, int N, int K, int epi,
    bf16* __restrict__ Qb, bf16* __restrict__ Kb, bf16* __restrict__ Vt,
    float* __restrict__ Out, const float* __restrict__ bias) {
  __shared__ bf16 lA[3][4096];  // 3 x (128 x 32)
  __shared__ bf16 lB[3][4096];
  const int tid = threadIdx.x, w = tid >> 6, l = tid & 63;
  const int m0 = blockIdx.x * 128, n0 = blockIdx.y * 128;
  const int wrow = (w >> 1) * 64, wcol = (w & 1) * 64;
  const int fr = l & 15, fq = l >> 4;
  f32x4 acc[4][4] = {};
  const int c0 = w * 64 + l, c1 = c0 + 256;  // 16B chunk ids
  const bf16* Ag0 = A + (size_t)(m0 + (c0 >> 2)) * K + (c0 & 3) * 8;
  const bf16* Ag1 = A + (size_t)(m0 + (c1 >> 2)) * K + (c1 & 3) * 8;
  const bf16* Bg0 = B + (size_t)(n0 + (c0 >> 2)) * K + (c0 & 3) * 8;
  const bf16* Bg1 = B + (size_t)(n0 + (c1 >> 2)) * K + (c1 & 3) * 8;
  bf16* lA0 = &lA[0][w * 512];
  bf16* lA1 = &lA[0][2048 + w * 512];
  bf16* lB0 = &lB[0][w * 512];
  bf16* lB1 = &lB[0][2048 + w * 512];

#define GSTAGE(T, BI)                                                          \
  do {                                                                         \
    const int ko_ = (T) * 32;                                                  \
    GLD_LDS16(Ag0 + ko_, lA0 + (BI) * 4096);                                   \
    GLD_LDS16(Ag1 + ko_, lA1 + (BI) * 4096);                                   \
    GLD_LDS16(Bg0 + ko_, lB0 + (BI) * 4096);                                   \
    GLD_LDS16(Bg1 + ko_, lB1 + (BI) * 4096);                                   \
  } while (0)

  const int nk = K >> 5;
  GSTAGE(0, 0);
  __builtin_amdgcn_sched_barrier(0);
  GSTAGE(1, 1);
  __builtin_amdgcn_sched_barrier(0);

  int bc_ = 0, bs_ = 2;
  for (int t = 0; t < nk; ++t) {
    asm volatile("s_waitcnt vmcnt(4)" ::: "memory");  // stage(t) done
    __builtin_amdgcn_s_barrier();                     // all waves' stage(t)
    __builtin_amdgcn_sched_barrier(0);
    int tt = (t + 2 < nk) ? t + 2 : nk - 1;  // clamp keeps count invariant
    GSTAGE(tt, bs_);
    __builtin_amdgcn_sched_barrier(0);
    const bf16* pA = &lA[bc_][0];
    const bf16* pB = &lB[bc_][0];
    short8 af[4], bfv[4];
#pragma unroll
    for (int mi = 0; mi < 4; ++mi)
      af[mi] = *(const short8*)&pA[(wrow + mi * 16 + fr) * 32 + fq * 8];
#pragma unroll
    for (int ni = 0; ni < 4; ++ni)
      bfv[ni] = *(const short8*)&pB[(wcol + ni * 16 + fr) * 32 + fq * 8];
    __builtin_amdgcn_s_setprio(1);
#pragma unroll
    for (int mi = 0; mi < 4; ++mi)
#pragma unroll
      for (int ni = 0; ni < 4; ++ni)
        acc[mi][ni] = mfma16(bfv[ni], af[mi], acc[mi][ni]);  // transposed
    __builtin_amdgcn_s_setprio(0);
    bc_ = (bc_ == 2) ? 0 : bc_ + 1;
    bs_ = (bs_ == 2) ? 0 : bs_ + 1;
  }
#undef GSTAGE

  if (epi == 0) {
#pragma unroll
    for (int mi = 0; mi < 4; ++mi)
#pragma unroll
      for (int ni = 0; ni < 4; ++ni) {
        int t = m0 + wrow + mi * 16 + fr;          // lane-fixed token
        int e4 = n0 + wcol + ni * 16 + fq * 4;     // 4 consecutive cols
        int sect = e4 >> 10, eh = (e4 >> 6) & 15, dh = e4 & 63;
        int b = t >> 11, tt = t & 2047;
        f32x4 a = acc[mi][ni];
        if (sect < 2) {
          size_t idx = (((size_t)b * 16 + eh) * 2048 + tt) * 64 + dh;
          float sc = (sect == 0) ? SCALE_Q : 1.f;  // pre-scale Q
          u32x2 ov;
          ov[0] = cvtpk(a[0] * sc, a[1] * sc);
          ov[1] = cvtpk(a[2] * sc, a[3] * sc);
          bf16* dst = (sect == 0) ? Qb : Kb;
          *(u32x2*)(dst + idx) = ov;
        } else {
          // V directly transposed: Vt[bh][d][t], 16-lane-contiguous 2B stores
          size_t vb = ((size_t)((b << 4) + eh) * 64 + dh) * 2048 + tt;
          unsigned p0 = cvtpk(a[0], a[1]);
          unsigned p1 = cvtpk(a[2], a[3]);
          unsigned short* vp = (unsigned short*)Vt;
          vp[vb] = (unsigned short)p0;
          vp[vb + 2048] = (unsigned short)(p0 >> 16);
          vp[vb + 4096] = (unsigned short)p1;
          vp[vb + 6144] = (unsigned short)(p1 >> 16);
        }
      }
  } else {
#pragma unroll
    for (int mi = 0; mi < 4; ++mi)
#pragma unroll
      for (int ni = 0; ni < 4; ++ni) {
        int t = m0 + wrow + mi * 16 + fr;
        int e4 = n0 + wcol + ni * 16 + fq * 4;
        f32x4 bv = *(const f32x4*)(bias + e4);
        f32x4 a = acc[mi][ni];
        f32x4 o = {a[0] + bv[0], a[1] + bv[1], a[2] + bv[2], a[3] + bv[3]};
        *(f32x4*)(Out + (size_t)t * N + e4) = o;
      }
  }
}

// ---------------- flash attention: KVBLK=128, T14 reg-staged write-late -----
// 256 thr = 4 waves, wave owns 32 q-rows; grid 512 (XCD-swizzled).
// Staging via registers (T14 async-STAGE split): global loads for tile t+1
// issued right after the bias loads (latency hides under QK+exp); the
// ds_write_b128s land AFTER PV, in the tile-end window where the LDS pipe is
// idle. Read side & data layout identical to the DMA version (pre-swizzled
// sources, linear LDS dest). Sync: lgkmcnt(0) + raw barrier per tile.
// Fixed softmax max (-16 baked into bias table); P built in-register
// (cvt_pk + permlane swap).
__global__ __launch_bounds__(256, 2) void k_attn(
    const bf16* __restrict__ Qb, const bf16* __restrict__ Kb,
    const bf16* __restrict__ Vt, const float* __restrict__ relpf,
    bf16* __restrict__ AO) {
  __shared__ bf16 lK[2][8192];  // [128 kv][64 d], chunk-XOR-swizzled
  __shared__ bf16 lV[2][8192];  // [64 d][128 kv], chunk-XOR-swizzled

  const int id = blockIdx.x;            // 0..511
  const int xcd = id & 7, j = id >> 3;  // j: 0..63
  const int bh = xcd * 4 + (j >> 4), qt = j & 15;
  const int h = bh & 15, b = bh >> 4;
  const int tid = threadIdx.x, w = tid >> 6, l = tid & 63;
  const int r32 = l & 31, hl = l >> 5, rs7 = r32 & 7;
  const int q0w = qt * 128 + w * 32;

  const bf16* Kbh = Kb + (size_t)bh * 2048 * 64;
  const bf16* Vbh = Vt + (size_t)bh * 64 * 2048;
  // staging geometry: 1024 chunks of 16B each for K and V; thread covers 4
  // of each. Source pre-swizzled, LDS dest linear (identical to DMA layout).
  const bf16* Ks[4];
  const bf16* Vs[4];
#pragma unroll
  for (int s = 0; s < 4; ++s) {
    int c = tid + 256 * s;
    int kr = c >> 3, kc = (c & 7) ^ (kr & 7);
    Ks[s] = Kbh + (size_t)kr * 64 + kc * 8;
    int vr = c >> 4, vc = (c & 15) ^ (vr & 7);
    Vs[s] = Vbh + (size_t)vr * 2048 + vc * 8;
  }

  u32x4 kreg[4], vreg[4];  // in-flight staging registers (32 VGPR)

#define LOADKV(KT)                                                             \
  do {                                                                         \
    _Pragma("unroll") for (int s_ = 0; s_ < 4; ++s_) {                         \
      kreg[s_] = *(const u32x4*)(Ks[s_] + (size_t)(KT) * 64);                  \
      vreg[s_] = *(const u32x4*)(Vs[s_] + (KT));                               \
    }                                                                          \
  } while (0)
#define WRITEKV(BI)                                                            \
  do {                                                                         \
    _Pragma("unroll") for (int s_ = 0; s_ < 4; ++s_) {                         \
      *(u32x4*)&lK[BI][(tid + 256 * s_) * 8] = kreg[s_];                       \
      *(u32x4*)&lV[BI][(tid + 256 * s_) * 8] = vreg[s_];                       \
    }                                                                          \
  } while (0)

  // Q as B-operand: col q = r32, k(d) = ks*16 + hl*8 + j  (pre-scaled)
  const bf16* Qp = Qb + ((size_t)bh * 2048 + q0w + r32) * 64;
  short8 qf[4];
#pragma unroll
  for (int ks = 0; ks < 4; ++ks)
    qf[ks] = *(const short8*)(Qp + ks * 16 + hl * 8);

  // bias: idx = kv - q + 2047; kv = kt + kb*32 + (reg&3) + 8*(reg>>2) + 4*hl
  const float* bp = relpf + h * 4096 + (2047 + 4 * hl - q0w - r32);

  float llane = 0.f;
  f32x16 o0 = {}, o1 = {};

  // prologue: stage tile 0 through regs
  LOADKV(0);
  WRITEKV(0);  // compiler inserts the vmcnt waits for kreg/vreg uses

  int cur = 0;
  for (int t = 0; t < 16; ++t) {
    const int kt = t * 128;
    asm volatile("s_waitcnt lgkmcnt(0)" ::: "memory");  // my ds_writes done
    __builtin_amdgcn_s_barrier();  // all waves' writes visible, reads done
    __builtin_amdgcn_sched_barrier(0);
    // bias for this tile first (older in queue), then next tile's kv loads
    // (newest -> exp's implicit bias wait leaves them in flight)
    f32x16 bc[4];
#pragma unroll
    for (int kb = 0; kb < 4; ++kb)
#pragma unroll
      for (int g = 0; g < 4; ++g) {
        f32x4u v = *(const f32x4u*)(bp + kt + kb * 32 + 8 * g);
#pragma unroll
        for (int e = 0; e < 4; ++e) bc[kb][g * 4 + e] = v[e];
      }
    __builtin_amdgcn_sched_barrier(0);
    if (t < 15) LOADKV(kt + 128);  // -> regs; latency hides under QK+exp
    __builtin_amdgcn_sched_barrier(0);
    const bf16* lKc = &lK[cur][0];
    const bf16* lVc = &lV[cur][0];
    // ---- S^T = K Q^T : 4 kv-blocks of 32
    f32x16 s[4] = {};
    __builtin_amdgcn_s_setprio(1);
#pragma unroll
    for (int kb = 0; kb < 4; ++kb)
#pragma unroll
      for (int ks = 0; ks < 4; ++ks) {
        short8 kf = *(const short8*)&lKc[(kb * 32 + r32) * 64 +
                                         (((2 * ks + hl) ^ rs7) * 8)];
        s[kb] = mfma32(kf, qf[ks], s[kb]);
      }
    __builtin_amdgcn_s_setprio(0);
    // ---- fixed-max softmax: P = exp2(s + bias'), bias' has -16 baked in
    float ra[4] = {0.f, 0.f, 0.f, 0.f};
#pragma unroll
    for (int kb = 0; kb < 4; ++kb)
#pragma unroll
      for (int reg = 0; reg < 16; ++reg) {
        float e = fexp2(s[kb][reg] + bc[kb][reg]);
        s[kb][reg] = e;
        ra[reg & 3] += e;
      }
    llane += (ra[0] + ra[1]) + (ra[2] + ra[3]);
    // ---- P-frags in-register + PV: O^T[d][q] += V^T P
#pragma unroll
    for (int kb = 0; kb < 4; ++kb) {
#pragma unroll
      for (int kh = 0; kh < 2; ++kh) {
        const int e = kh * 8;
        unsigned a0 = cvtpk(s[kb][e + 0], s[kb][e + 1]);
        unsigned a1 = cvtpk(s[kb][e + 2], s[kb][e + 3]);
        unsigned b0 = cvtpk(s[kb][e + 4], s[kb][e + 5]);
        unsigned b1 = cvtpk(s[kb][e + 6], s[kb][e + 7]);
        PLSWAP(a0, b0);  // distinct values: no coalescing hazard
        PLSWAP(a1, b1);
        u32x4 pw = {a0, a1, b0, b1};
        short8 pf = __builtin_bit_cast(short8, pw);
        const int ks = kb * 2 + kh;
        const int cc = ((2 * ks + hl) ^ rs7) * 8;
        short8 v0 = *(const short8*)&lVc[r32 * 128 + cc];
        short8 v1 = *(const short8*)&lVc[(32 + r32) * 128 + cc];
        __builtin_amdgcn_s_setprio(1);
        o0 = mfma32(v0, pf, o0);
        o1 = mfma32(v1, pf, o1);
        __builtin_amdgcn_s_setprio(0);
      }
    }
    __builtin_amdgcn_sched_barrier(0);
    if (t < 15) WRITEKV(cur ^ 1);  // write-late: LDS pipe idle post-PV
    cur ^= 1;
  }
#undef LOADKV
#undef WRITEKV

  // lane: q = r32; o[db][reg] = O^T[d = db*32 + (reg&3)+8*(reg>>2)+4*hl][q]
  float lsum = llane + __shfl_xor(llane, 32);  // pair-combine once
  float rin = 1.f / lsum;
  bf16* aor = AO + ((size_t)(b * 2048 + q0w + r32)) * 1024 + h * 64 + hl * 4;
#pragma unroll
  for (int rg = 0; rg < 4; ++rg) {
    u32x2 ov0, ov1;
    ov0[0] = cvtpk(o0[4 * rg + 0] * rin, o0[4 * rg + 1] * rin);
    ov0[1] = cvtpk(o0[4 * rg + 2] * rin, o0[4 * rg + 3] * rin);
    *(u32x2*)(aor + rg * 8) = ov0;
    ov1[0] = cvtpk(o1[4 * rg + 0] * rin, o1[4 * rg + 1] * rin);
    ov1[1] = cvtpk(o1[4 * rg + 2] * rin, o1[4 * rg + 3] * rin);
    *(u32x2*)(aor + 32 + rg * 8) = ov1;
  }
}

// ---------------------------------------------------------------------------
extern "C" void kernel_launch(void* const* d_in, const int* in_sizes, int n_in,
                              void* d_out, int out_size, void* d_ws,
                              size_t ws_size, hipStream_t stream) {
  const float* x = (const float*)d_in[0];     // [2,2048,1024]
  const float* Wqkv = (const float*)d_in[1];  // [3072,1024]
  const float* Wout = (const float*)d_in[2];  // [1024,1024]
  const float* bout = (const float*)d_in[3];  // [1024]
  const float* rel = (const float*)d_in[4];   // [2049,16]
  float* out = (float*)d_out;

  char* p = (char*)d_ws;
  bf16* xb  = (bf16*)(p);                      // 8 MB  [4096][1024]
  bf16* wqb = (bf16*)(p + (8ull << 20));       // 6 MB  [3072][1024]
  bf16* wob = (bf16*)(p + (14ull << 20));      // 2 MB  [1024][1024]
  bf16* Qb  = (bf16*)(p + (16ull << 20));      // 8 MB  [32][2048][64]
  bf16* Kb  = (bf16*)(p + (24ull << 20));      // 8 MB
  bf16* Vtr = (bf16*)(p + (32ull << 20));      // 8 MB  [32][64][2048]
  bf16* aob = (bf16*)(p + (40ull << 20));      // 8 MB  [4096][1024]
  float* relpf = (float*)(p + (48ull << 20));  // 256 KB [16][4096] f32

  k_pre<<<4160, 256, 0, stream>>>(x, Wqkv, Wout, rel, xb, wqb, wob, relpf);
  k_gemm<<<dim3(32, 24), 256, 0, stream>>>(xb, wqb, 4096, 3072, 1024, 0,
                                           Qb, Kb, Vtr, nullptr, nullptr);
  k_attn<<<512, 256, 0, stream>>>(Qb, Kb, Vtr, relpf, aob);
  k_gemm<<<dim3(32, 8), 256, 0, stream>>>(aob, wob, 4096, 1024, 1024, 1,
                                          nullptr, nullptr, nullptr, out, bout);
}